// Round 10
// baseline (77.361 us; speedup 1.0000x reference)
//
#include <hip/hip_runtime.h>

// Problem constants (fixed by setup_inputs / reference)
#define FH 2160
#define FW 3840
#define DH 1080
#define DW 1920
#define RAD 8
#define KS 17
#define INV_KS (1.0f / 17.0f)
#define EPS_GF 1e-3f
#define EPS_LOG 1e-6f
#define EPS_SCALE 1e-4f
#define A_COEF 0.7f

// K1 geometry: 32x32 core of D/a/b per block, D halo tile 48x48 built from x 96x96
#define TS 32
#define IT 48               // TS + 2*RAD
#define ITP 50              // EVEN padded stride (float2-aligned strip reads)
#define NT1 2040            // 60 x 34 tiles
#define TPX1 255            // tiles per XCD

// K2 geometry: 64x32 output px per block; base tile 18x34 (16x32 core + bilinear +/-1);
// a/b tile 34x50
#define ATR 34              // AB rows
#define ATC 50              // AB cols
#define ATP2 52             // even float2 stride, cols 50/51 = tail padding
#define BTC 34              // base cols
#define BTR 18              // base rows
#define BTP 35
#define NT2 4080            // 60 x 68 tiles (% 8 == 0)
#define TPX2 510

__device__ __forceinline__ int refl(int p, int n) {
    // jnp.pad 'reflect' (no edge repeat). Max overhang 17 << n, one fold suffices.
    p = (p < 0) ? -p : p;
    return (p >= n) ? (2 * n - 2 - p) : p;
}

__device__ __forceinline__ float luma3(float r, float g, float b) {
    return 0.2126f * r + 0.7152f * g + 0.0722f * b;
}

// ---- K1: x -> D, {a,b}  (downsample fused with GF stage 1) ----
__global__ void __launch_bounds__(256)
k_gf_front(const float* __restrict__ x, float* __restrict__ Dg,
           float2* __restrict__ ABg) {
    __shared__ float inD[IT * ITP];   // 48x50 = 9.6 KB
    __shared__ float2 hh[IT * TS];    // 48x32 f2 = 12.3 KB  (.x = I taps, .y = I*I taps)
    int bid = blockIdx.x;
    int swz = (bid & 7) * TPX1 + (bid >> 3);   // XCD-contiguous raster strips
    int bx = swz % 60, by = swz / 60;
    int tx0 = bx * TS, ty0 = by * TS;
    int t = threadIdx.x;

    // Phase 1: D halo tile from x (luma -> log2 -> 2x2 mean).
    // DOWN=0.5 align_corners=False bilinear == exact 2x2 mean; sum of 4 log2 == log2 of product.
    for (int s = t; s < IT * IT; s += 256) {
        int li = s / IT, lj = s - li * IT;
        int gi = refl(ty0 - RAD + li, DH);
        int gj = refl(tx0 - RAD + lj, DW);
        const float* p0 = x + ((size_t)(2 * gi) * FW + (size_t)(2 * gj)) * 3;
        const float* p1 = p0 + (size_t)FW * 3;
        float2 a0 = *(const float2*)(p0);
        float2 a1 = *(const float2*)(p0 + 2);
        float2 a2 = *(const float2*)(p0 + 4);
        float2 b0 = *(const float2*)(p1);
        float2 b1 = *(const float2*)(p1 + 2);
        float2 b2 = *(const float2*)(p1 + 4);
        float y00 = fmaxf(luma3(a0.x, a0.y, a1.x), EPS_LOG);
        float y01 = fmaxf(luma3(a1.y, a2.x, a2.y), EPS_LOG);
        float y10 = fmaxf(luma3(b0.x, b0.y, b1.x), EPS_LOG);
        float y11 = fmaxf(luma3(b1.y, b2.x, b2.y), EPS_LOG);
        inD[li * ITP + lj] = 0.25f * __log2f((y00 * y01) * (y10 * y11));
    }
    __syncthreads();

    // Phase 2: hbox of I and I*I, strip-4 sliding. tasks = 48 rows x 8 strips = 384
    for (int task = t; task < IT * 8; task += 256) {
        int r = task >> 3, c0 = (task & 7) * 4;
        const float* row = &inD[r * ITP + c0];
        const float2* row2 = (const float2*)row;   // (r*50 + c0) even -> 8B aligned
        float s1 = 0.f, s2 = 0.f;
#pragma unroll
        for (int k = 0; k < 8; ++k) {
            float2 p = row2[k];
            s1 += p.x + p.y;
            s2 += p.x * p.x + p.y * p.y;
        }
        float v16 = row[16];
        s1 += v16; s2 += v16 * v16;
        int base = r * TS + c0;
        hh[base] = make_float2(s1 * INV_KS, s2 * INV_KS);
#pragma unroll
        for (int cc = 1; cc < 4; ++cc) {
            float vo = row[cc - 1], vi = row[cc + 16];
            s1 += vi - vo;
            s2 += vi * vi - vo * vo;
            hh[base + cc] = make_float2(s1 * INV_KS, s2 * INV_KS);
        }
    }
    __syncthreads();

    // Phase 3: vbox strip-4 -> a,b ; also write D core. tasks = 8 rstrips x 32 cols = 256
    {
        int rs = t >> 5, c = t & 31;
        int r0 = rs * 4;
        float sx = 0.f, sy = 0.f;
#pragma unroll
        for (int k = 0; k < KS; ++k) {
            float2 h = hh[(r0 + k) * TS + c];
            sx += h.x; sy += h.y;
        }
#pragma unroll
        for (int rr = 0; rr < 4; ++rr) {
            int r = r0 + rr;
            if (rr > 0) {
                float2 hi = hh[(r + 16) * TS + c];
                float2 ho = hh[(r - 1) * TS + c];
                sx += hi.x - ho.x;
                sy += hi.y - ho.y;
            }
            int gi = ty0 + r;
            if (gi < DH) {
                float mI = sx * INV_KS, mII = sy * INV_KS;
                float var = mII - mI * mI;
                float av = var * __builtin_amdgcn_rcpf(var + EPS_GF);
                size_t g = (size_t)gi * DW + tx0 + c;
                ABg[g] = make_float2(av, mI - av * mI);
                Dg[g] = inD[(r + RAD) * ITP + c + RAD];
            }
        }
    }
}

// ---- epilogue for one quad of 4 px, structured DOWN=0.5 bilinear weights ----
// wx,wy in {0.25,0.75}; index clamps reproduce the reference's coordinate clamps exactly.
__device__ __forceinline__ void epi_quad(int oy, int qi,
                                         int jm1, int j0, int jp1, int jp2,
                                         const float* baseT,
                                         float4 v0, float4 v1, float4 v2,
                                         float* __restrict__ out, size_t off) {
    int ny = oy >> 1;
    int h = qi >> 1;
    int rA, rB;
    float wA, wB;
    if (oy & 1) {
        rA = h + 1;
        rB = (ny + 1 <= DH - 1) ? h + 2 : h + 1;
        wA = 0.75f; wB = 0.25f;
    } else {
        rA = (ny >= 1) ? h : h + 1;
        rB = h + 1;
        wA = 0.25f; wB = 0.75f;
    }
    const float* brA = &baseT[rA * BTP];
    const float* brB = &baseT[rB * BTP];
    float Vm1 = wA * brA[jm1] + wB * brB[jm1];
    float V0  = wA * brA[j0]  + wB * brB[j0];
    float Vp1 = wA * brA[jp1] + wB * brB[jp1];
    float Vp2 = wA * brA[jp2] + wB * brB[jp2];
    float Ybs[4] = {0.25f * Vm1 + 0.75f * V0,
                    0.75f * V0  + 0.25f * Vp1,
                    0.25f * V0  + 0.75f * Vp1,
                    0.75f * Vp1 + 0.25f * Vp2};
    float px[12] = {v0.x, v0.y, v0.z, v0.w, v1.x, v1.y, v1.z, v1.w,
                    v2.x, v2.y, v2.z, v2.w};
    float po[12];
#pragma unroll
    for (int p = 0; p < 4; ++p) {
        float cr = px[3 * p], cg = px[3 * p + 1], cb = px[3 * p + 2];
        float Y = luma3(cr, cg, cb);
        float Ylog = __log2f(fmaxf(Y, EPS_LOG));
        float Yb = Ybs[p];
        float Yout = exp2f(A_COEF * Yb + (Ylog - Yb));
        float sc = Yout * __builtin_amdgcn_rcpf(Y + EPS_SCALE);
        po[3 * p + 0] = fminf(fmaxf(cr * sc, 0.f), 1.f);
        po[3 * p + 1] = fminf(fmaxf(cg * sc, 0.f), 1.f);
        po[3 * p + 2] = fminf(fmaxf(cb * sc, 0.f), 1.f);
    }
    float4* op = (float4*)(out + off);
    op[0] = make_float4(po[0], po[1], po[2], po[3]);
    op[1] = make_float4(po[4], po[5], po[6], po[7]);
    op[2] = make_float4(po[8], po[9], po[10], po[11]);
}

// ---- K2: {a,b},D,x -> out  (GF stage 2 fused with upsample + tonemap) ----
__global__ void __launch_bounds__(256)
k_gf_back(const float* __restrict__ x, const float2* __restrict__ ABg,
          const float* __restrict__ Dg, float* __restrict__ out) {
    __shared__ float2 inAB[ATR * ATP2];   // 34x52 f2 = 14.1 KB (cols 50/51 pad)
    __shared__ float2 hAB[ATR * BTC];     // 34x34 f2 = 9.2 KB
    __shared__ float baseT[BTR * BTP];    // 18x35 = 2.5 KB
    int bid = blockIdx.x;
    int swz = (bid & 7) * TPX2 + (bid >> 3);
    int bx = swz % 60, by = swz / 60;     // bx 0..59, by 0..67
    int ox0 = bx * 64, oy0 = by * 32;
    int bh0 = by * 16 - 1, bw0 = bx * 32 - 1;   // base tile origin (incl -1 bilinear halo)
    int ah0 = bh0 - RAD, aw0 = bw0 - RAD;       // a/b tile origin
    int t = threadIdx.x;

    // Phase -1: T14 async-stage — issue this thread's epilogue x loads NOW so their
    // latency hides under the GF phases. 2 quads/thread, 3 float4 each (static map).
    int qi0 = t >> 4, qj = t & 15;
    int oy_0 = oy0 + qi0;            // always < FH
    int oy_1 = oy_0 + 16;            // may exceed FH only in last tile row
    size_t off0 = ((size_t)oy_0 * FW + (size_t)(ox0 + 4 * qj)) * 3;
    size_t off1 = (oy_1 < FH) ? ((size_t)oy_1 * FW + (size_t)(ox0 + 4 * qj)) * 3 : off0;
    const float4* xin0 = (const float4*)(x + off0);
    const float4* xin1 = (const float4*)(x + off1);
    float4 xa0 = xin0[0], xa1 = xin0[1], xa2 = xin0[2];
    float4 xb0 = xin1[0], xb1 = xin1[1], xb2 = xin1[2];

    // Phase 0: gather AB tile 34x50 (fast path for interior blocks: no refl)
    if (ah0 >= 0 && ah0 + ATR <= DH && aw0 >= 0 && aw0 + ATC <= DW) {
        const float2* src = ABg + (size_t)ah0 * DW + aw0;
        for (int s = t; s < ATR * ATC; s += 256) {
            int li = s / ATC, lj = s - li * ATC;
            inAB[li * ATP2 + lj] = src[(size_t)li * DW + lj];
        }
    } else {
        for (int s = t; s < ATR * ATC; s += 256) {
            int li = s / ATC, lj = s - li * ATC;
            inAB[li * ATP2 + lj] = ABg[(size_t)refl(ah0 + li, DH) * DW + refl(aw0 + lj, DW)];
        }
    }
    __syncthreads();

    // Phase 1: hbox strip-4. tasks = 34 rows x 9 strips = 306. Tail strip (c0=32)
    // slides into in-row padding (stale) AFTER its last in-range write -> harmless.
    for (int task = t; task < ATR * 9; task += 256) {
        int r = task / 9, c0 = (task - r * 9) * 4;
        const float2* row = &inAB[r * ATP2 + c0];
        float s1 = 0.f, s2 = 0.f;
#pragma unroll
        for (int k = 0; k < KS; ++k) { float2 v = row[k]; s1 += v.x; s2 += v.y; }
        int base = r * BTC + c0;
#pragma unroll
        for (int cc = 0; cc < 4; ++cc) {
            if (cc > 0) {
                float2 vi = row[cc + 16], vo = row[cc - 1];
                s1 += vi.x - vo.x;
                s2 += vi.y - vo.y;
            }
            if (c0 + cc < BTC) hAB[base + cc] = make_float2(s1 * INV_KS, s2 * INV_KS);
        }
    }
    __syncthreads();

    // Phase 2: vbox, 5 row-strips of sizes {4,4,4,4,2}. tasks = 5 x 34 = 170.
    for (int task = t; task < 5 * BTC; task += 256) {
        int rs = task / BTC, c = task - rs * BTC;
        int r0 = rs * 4;
        int sz = (rs == 4) ? 2 : 4;
        float s1 = 0.f, s2 = 0.f;
#pragma unroll
        for (int k = 0; k < KS; ++k) {
            float2 v = hAB[(r0 + k) * BTC + c];
            s1 += v.x; s2 += v.y;
        }
        for (int rr = 0; rr < sz; ++rr) {
            int r = r0 + rr;
            if (rr > 0) {
                float2 vi = hAB[(r + 16) * BTC + c];
                float2 vo = hAB[(r - 1) * BTC + c];
                s1 += vi.x - vo.x;
                s2 += vi.y - vo.y;
            }
            size_t g = (size_t)refl(bh0 + r, DH) * DW + refl(bw0 + c, DW);
            baseT[r * BTP + c] = (s1 * INV_KS) * Dg[g] + s2 * INV_KS;
        }
    }
    __syncthreads();

    // Phase 3: epilogue from prefetched x + LDS base (structured bilinear)
    {
        int mq = bx * 32 + 2 * qj;
        int jm1 = max(mq - 1, 0) - bw0;
        int j0 = mq - bw0;
        int jp1 = min(mq + 1, DW - 1) - bw0;
        int jp2 = min(mq + 2, DW - 1) - bw0;
        epi_quad(oy_0, qi0, jm1, j0, jp1, jp2, baseT, xa0, xa1, xa2, out, off0);
        if (oy_1 < FH)
            epi_quad(oy_1, qi0 + 16, jm1, j0, jp1, jp2, baseT, xb0, xb1, xb2, out, off1);
    }
}

extern "C" void kernel_launch(void* const* d_in, const int* in_sizes, int n_in,
                              void* d_out, int out_size, void* d_ws, size_t ws_size,
                              hipStream_t stream) {
    const float* x = (const float*)d_in[0];
    float* out = (float*)d_out;
    float* ws = (float*)d_ws;
    const size_t DN = (size_t)DW * DH;  // 8.29 MB

    float* D = ws;                        // DN floats
    float2* AB = (float2*)(ws + DN);      // DN float2

    k_gf_front<<<dim3(NT1), dim3(256), 0, stream>>>(x, D, AB);
    k_gf_back <<<dim3(NT2), dim3(256), 0, stream>>>(x, AB, D, out);
}

// Round 11
// 71.383 us; speedup vs baseline: 1.0838x; 1.0838x over previous
//
#include <hip/hip_runtime.h>

// Problem constants (fixed by setup_inputs / reference)
#define FH 2160
#define FW 3840
#define DH 1080
#define DW 1920
#define RAD 8
#define KS 17
#define INV_KS (1.0f / 17.0f)
#define EPS_GF 1e-3f
#define EPS_LOG 1e-6f
#define EPS_SCALE 1e-4f
#define A_COEF 0.7f

// K1 geometry: 32x32 core of D/a/b per block, D halo tile 48x48 built from x 96x96
#define TS 32
#define IT 48               // TS + 2*RAD
#define ITP 50              // EVEN padded stride (float2-aligned strip reads)
#define NT1 2040            // 60 x 34 tiles
#define TPX1 255            // tiles per XCD

// K2 geometry: 64x32 output px per block; base tile 18x34 (16x32 core + bilinear +/-1);
// a/b tile 34x50
#define ATR 34              // AB rows
#define ATC 50              // AB cols
#define ATP2 52             // even float2 stride, cols 50/51 = tail padding
#define BTC 34              // base cols
#define BTR 18              // base rows
#define BTP 35
#define NT2 4080            // 60 x 68 tiles (% 8 == 0)
#define TPX2 510

__device__ __forceinline__ int refl(int p, int n) {
    // jnp.pad 'reflect' (no edge repeat). Max overhang 17 << n, one fold suffices.
    p = (p < 0) ? -p : p;
    return (p >= n) ? (2 * n - 2 - p) : p;
}

__device__ __forceinline__ float luma3(float r, float g, float b) {
    return 0.2126f * r + 0.7152f * g + 0.0722f * b;
}

// ---- K1: x -> D, {a,b}  (downsample fused with GF stage 1) ----
__global__ void __launch_bounds__(256)
k_gf_front(const float* __restrict__ x, float* __restrict__ Dg,
           float2* __restrict__ ABg) {
    __shared__ float inD[IT * ITP];   // 48x50 = 9.6 KB
    __shared__ float2 hh[IT * TS];    // 48x32 f2 = 12.3 KB  (.x = I taps, .y = I*I taps)
    int bid = blockIdx.x;
    int swz = (bid & 7) * TPX1 + (bid >> 3);   // XCD-contiguous raster strips
    int bx = swz % 60, by = swz / 60;
    int tx0 = bx * TS, ty0 = by * TS;
    int t = threadIdx.x;

    // Phase 1: D halo tile from x (luma -> log2 -> 2x2 mean).
    // DOWN=0.5 align_corners=False bilinear == exact 2x2 mean; sum of 4 log2 == log2 of product.
    for (int s = t; s < IT * IT; s += 256) {
        int li = s / IT, lj = s - li * IT;
        int gi = refl(ty0 - RAD + li, DH);
        int gj = refl(tx0 - RAD + lj, DW);
        const float* p0 = x + ((size_t)(2 * gi) * FW + (size_t)(2 * gj)) * 3;
        const float* p1 = p0 + (size_t)FW * 3;
        float2 a0 = *(const float2*)(p0);
        float2 a1 = *(const float2*)(p0 + 2);
        float2 a2 = *(const float2*)(p0 + 4);
        float2 b0 = *(const float2*)(p1);
        float2 b1 = *(const float2*)(p1 + 2);
        float2 b2 = *(const float2*)(p1 + 4);
        float y00 = fmaxf(luma3(a0.x, a0.y, a1.x), EPS_LOG);
        float y01 = fmaxf(luma3(a1.y, a2.x, a2.y), EPS_LOG);
        float y10 = fmaxf(luma3(b0.x, b0.y, b1.x), EPS_LOG);
        float y11 = fmaxf(luma3(b1.y, b2.x, b2.y), EPS_LOG);
        inD[li * ITP + lj] = 0.25f * __log2f((y00 * y01) * (y10 * y11));
    }
    __syncthreads();

    // Phase 2: hbox of I and I*I, strip-4 sliding. tasks = 48 rows x 8 strips = 384
    for (int task = t; task < IT * 8; task += 256) {
        int r = task >> 3, c0 = (task & 7) * 4;
        const float* row = &inD[r * ITP + c0];
        const float2* row2 = (const float2*)row;   // (r*50 + c0) even -> 8B aligned
        float s1 = 0.f, s2 = 0.f;
#pragma unroll
        for (int k = 0; k < 8; ++k) {
            float2 p = row2[k];
            s1 += p.x + p.y;
            s2 += p.x * p.x + p.y * p.y;
        }
        float v16 = row[16];
        s1 += v16; s2 += v16 * v16;
        int base = r * TS + c0;
        hh[base] = make_float2(s1 * INV_KS, s2 * INV_KS);
#pragma unroll
        for (int cc = 1; cc < 4; ++cc) {
            float vo = row[cc - 1], vi = row[cc + 16];
            s1 += vi - vo;
            s2 += vi * vi - vo * vo;
            hh[base + cc] = make_float2(s1 * INV_KS, s2 * INV_KS);
        }
    }
    __syncthreads();

    // Phase 3: vbox strip-4 -> a,b ; also write D core. tasks = 8 rstrips x 32 cols = 256
    {
        int rs = t >> 5, c = t & 31;
        int r0 = rs * 4;
        float sx = 0.f, sy = 0.f;
#pragma unroll
        for (int k = 0; k < KS; ++k) {
            float2 h = hh[(r0 + k) * TS + c];
            sx += h.x; sy += h.y;
        }
#pragma unroll
        for (int rr = 0; rr < 4; ++rr) {
            int r = r0 + rr;
            if (rr > 0) {
                float2 hi = hh[(r + 16) * TS + c];
                float2 ho = hh[(r - 1) * TS + c];
                sx += hi.x - ho.x;
                sy += hi.y - ho.y;
            }
            int gi = ty0 + r;
            if (gi < DH) {
                float mI = sx * INV_KS, mII = sy * INV_KS;
                float var = mII - mI * mI;
                float av = var * __builtin_amdgcn_rcpf(var + EPS_GF);
                size_t g = (size_t)gi * DW + tx0 + c;
                ABg[g] = make_float2(av, mI - av * mI);
                Dg[g] = inD[(r + RAD) * ITP + c + RAD];
            }
        }
    }
}

// ---- K2: {a,b},D,x -> out  (GF stage 2 fused with upsample + tonemap) ----
// 64x32 output px per block; LDS 25.9 KB -> 6 blocks/CU.
__global__ void __launch_bounds__(256)
k_gf_back(const float* __restrict__ x, const float2* __restrict__ ABg,
          const float* __restrict__ Dg, float* __restrict__ out) {
    __shared__ float2 inAB[ATR * ATP2];   // 34x52 f2 = 14.1 KB (cols 50/51 pad)
    __shared__ float2 hAB[ATR * BTC];     // 34x34 f2 = 9.2 KB
    __shared__ float baseT[BTR * BTP];    // 18x35 = 2.5 KB
    int bid = blockIdx.x;
    int swz = (bid & 7) * TPX2 + (bid >> 3);
    int bx = swz % 60, by = swz / 60;     // bx 0..59, by 0..67
    int ox0 = bx * 64, oy0 = by * 32;
    int bh0 = by * 16 - 1, bw0 = bx * 32 - 1;   // base tile origin (incl -1 bilinear halo)
    int ah0 = bh0 - RAD, aw0 = bw0 - RAD;       // a/b tile origin
    int t = threadIdx.x;

    // Phase 0: gather AB tile 34x50; interior fast path (~92% of blocks) skips refl
    if (ah0 >= 0 && ah0 + ATR <= DH && aw0 >= 0 && aw0 + ATC <= DW) {
        const float2* src = ABg + (size_t)ah0 * DW + aw0;
        for (int s = t; s < ATR * ATC; s += 256) {
            int li = s / ATC, lj = s - li * ATC;
            inAB[li * ATP2 + lj] = src[(size_t)li * DW + lj];
        }
    } else {
        for (int s = t; s < ATR * ATC; s += 256) {
            int li = s / ATC, lj = s - li * ATC;
            inAB[li * ATP2 + lj] = ABg[(size_t)refl(ah0 + li, DH) * DW + refl(aw0 + lj, DW)];
        }
    }
    __syncthreads();

    // Phase 1: hbox strip-4. tasks = 34 rows x 9 strips = 306. Tail strip (c0=32)
    // slides into in-row padding (stale) AFTER its last in-range write -> harmless.
    for (int task = t; task < ATR * 9; task += 256) {
        int r = task / 9, c0 = (task - r * 9) * 4;
        const float2* row = &inAB[r * ATP2 + c0];
        float s1 = 0.f, s2 = 0.f;
#pragma unroll
        for (int k = 0; k < KS; ++k) { float2 v = row[k]; s1 += v.x; s2 += v.y; }
        int base = r * BTC + c0;
#pragma unroll
        for (int cc = 0; cc < 4; ++cc) {
            if (cc > 0) {
                float2 vi = row[cc + 16], vo = row[cc - 1];
                s1 += vi.x - vo.x;
                s2 += vi.y - vo.y;
            }
            if (c0 + cc < BTC) hAB[base + cc] = make_float2(s1 * INV_KS, s2 * INV_KS);
        }
    }
    __syncthreads();

    // Phase 2: vbox, 5 row-strips of sizes {4,4,4,4,2}. tasks = 5 x 34 = 170.
    for (int task = t; task < 5 * BTC; task += 256) {
        int rs = task / BTC, c = task - rs * BTC;
        int r0 = rs * 4;
        int sz = (rs == 4) ? 2 : 4;
        float s1 = 0.f, s2 = 0.f;
#pragma unroll
        for (int k = 0; k < KS; ++k) {
            float2 v = hAB[(r0 + k) * BTC + c];
            s1 += v.x; s2 += v.y;
        }
        for (int rr = 0; rr < sz; ++rr) {
            int r = r0 + rr;
            if (rr > 0) {
                float2 vi = hAB[(r + 16) * BTC + c];
                float2 vo = hAB[(r - 1) * BTC + c];
                s1 += vi.x - vo.x;
                s2 += vi.y - vo.y;
            }
            size_t g = (size_t)refl(bh0 + r, DH) * DW + refl(bw0 + c, DW);
            baseT[r * BTP + c] = (s1 * INV_KS) * Dg[g] + s2 * INV_KS;
        }
    }
    __syncthreads();

    // Phase 3: upsample base from LDS + tonemap + scale + clip; 32 rows x 16 quads
    for (int q = t; q < 32 * 16; q += 256) {
        int qi = q >> 4, qj = q & 15;
        int oy = oy0 + qi;
        if (oy < FH) {
            float ys = fminf(fmaxf((oy + 0.5f) * 0.5f - 0.5f, 0.f), (float)(DH - 1));
            int y0 = (int)ys;
            int y1 = min(y0 + 1, DH - 1);
            float wy = ys - (float)y0;
            const float* br0 = &baseT[(y0 - bh0) * BTP];
            const float* br1 = &baseT[(y1 - bh0) * BTP];

            size_t off = ((size_t)oy * FW + (size_t)(ox0 + 4 * qj)) * 3;
            const float4* xin = (const float4*)(x + off);
            float4 v0 = xin[0], v1 = xin[1], v2 = xin[2];
            float px[12] = {v0.x, v0.y, v0.z, v0.w, v1.x, v1.y, v1.z, v1.w,
                            v2.x, v2.y, v2.z, v2.w};
            float po[12];
#pragma unroll
            for (int p = 0; p < 4; ++p) {
                int ox = ox0 + 4 * qj + p;
                float xs = fminf(fmaxf((ox + 0.5f) * 0.5f - 0.5f, 0.f), (float)(DW - 1));
                int x0 = (int)xs;
                int x1 = min(x0 + 1, DW - 1);
                float wx = xs - (float)x0;
                int c0 = x0 - bw0, c1 = x1 - bw0;
                float top = br0[c0] * (1.f - wx) + br0[c1] * wx;
                float bot = br1[c0] * (1.f - wx) + br1[c1] * wx;
                float Yb = top * (1.f - wy) + bot * wy;

                float cr = px[3 * p], cg = px[3 * p + 1], cb = px[3 * p + 2];
                float Y = luma3(cr, cg, cb);
                float Ylog = __log2f(fmaxf(Y, EPS_LOG));
                float Yout = exp2f(A_COEF * Yb + (Ylog - Yb));
                float sc = Yout * __builtin_amdgcn_rcpf(Y + EPS_SCALE);
                po[3 * p + 0] = fminf(fmaxf(cr * sc, 0.f), 1.f);
                po[3 * p + 1] = fminf(fmaxf(cg * sc, 0.f), 1.f);
                po[3 * p + 2] = fminf(fmaxf(cb * sc, 0.f), 1.f);
            }
            float4* op = (float4*)(out + off);
            op[0] = make_float4(po[0], po[1], po[2], po[3]);
            op[1] = make_float4(po[4], po[5], po[6], po[7]);
            op[2] = make_float4(po[8], po[9], po[10], po[11]);
        }
    }
}

extern "C" void kernel_launch(void* const* d_in, const int* in_sizes, int n_in,
                              void* d_out, int out_size, void* d_ws, size_t ws_size,
                              hipStream_t stream) {
    const float* x = (const float*)d_in[0];
    float* out = (float*)d_out;
    float* ws = (float*)d_ws;
    const size_t DN = (size_t)DW * DH;  // 8.29 MB

    float* D = ws;                        // DN floats
    float2* AB = (float2*)(ws + DN);      // DN float2

    k_gf_front<<<dim3(NT1), dim3(256), 0, stream>>>(x, D, AB);
    k_gf_back <<<dim3(NT2), dim3(256), 0, stream>>>(x, AB, D, out);
}